// Round 9
// baseline (129.114 us; speedup 1.0000x reference)
//
#include <hip/hip_runtime.h>
#include <hip/hip_fp16.h>

// Problem constants (fixed by the reference setup)
constexpr int N = 4096;
constexpr int D = 512;
constexpr int NT = 32;                   // 4096 / 128 tile-rows
constexpr int NBLK = NT * (NT + 1) / 2;  // 528 upper-triangle tiles
constexpr float SENT = -1e30f;           // sentinel (invalid sites / empty slots)
constexpr unsigned TCV = 8386560u;       // N*(N-1)/2 valid strict-upper pairs

// Prefilter threshold: sims ~ N(0, 1/512); loss >= 0.60 <=> ~2.26 sigma =>
// ~194 candidates per full 128x128 block, ~97 per diagonal block. CCAP=320
// is +9 sigma. Exactness NEVER depends on T0: out-of-range counts take the
// exact binary-search fallback below.
constexpr float T0 = 0.60f;
constexpr unsigned CCAP = 320;

typedef _Float16 f16x8 __attribute__((ext_vector_type(8)));
typedef float f32x4 __attribute__((ext_vector_type(4)));

// Exact wave top-10 by repeated selection over per-lane register candidates.
// out[r] ends up wave-uniform. Duplicates preserved (leader pops ONE copy).
// NOTE: mutates vals[] on leader lanes.
template <int M>
__device__ __forceinline__ void wave_sel10(float (&vals)[M], float (&out)[10]) {
  int lane = threadIdx.x & 63;
  float lm = vals[0];
#pragma unroll
  for (int k = 1; k < M; k++) lm = fmaxf(lm, vals[k]);
#pragma unroll
  for (int r = 0; r < 10; r++) {
    float wmx = lm;
#pragma unroll
    for (int ofs = 1; ofs < 64; ofs <<= 1)
      wmx = fmaxf(wmx, __shfl_xor(wmx, ofs));
    out[r] = wmx;
    unsigned long long b = __ballot(lm == wmx);
    int leader = __ffsll(b) - 1;
    if (lane == leader) {
      bool found = false;
#pragma unroll
      for (int k = 0; k < M; k++) {
        bool hit = !found && (vals[k] == wmx);
        vals[k] = hit ? SENT : vals[k];
        found = found || hit;
      }
      lm = vals[0];
#pragma unroll
      for (int k = 1; k < M; k++) lm = fmaxf(lm, vals[k]);
    }
  }
}

// ws layout (float indices unless noted):
//   [0, 528)       f32 blk_sumv
//   [528, 1056)    f32 blk_sump
//   [1056, 1584)   u32 cntpack  (cntp | zeros<<16; per-block totals <= 16384)
//   [1584, 2112)   f32 bmax[528]       per-block max loss (finalize prune)
//   [2112, 7392)   f32 top10g[528*10]
//   byte 32768:    f16 Xh[N*D]
constexpr int BMAX_IDX = 3 * NBLK;
constexpr int TOP10G_IDX = 4 * NBLK;
constexpr int XH_OFF = 32768;

// ---------------- K0: fp32 -> f16 convert ----------------
__global__ void prep_kernel(const float4* __restrict__ X4,
                            ushort4* __restrict__ Xh4) {
  int gid = blockIdx.x * 256 + threadIdx.x;  // grid exactly N*D/4 threads
  float4 v = X4[gid];
  ushort4 o;
  o.x = __half_as_ushort(__float2half_rn(v.x));
  o.y = __half_as_ushort(__float2half_rn(v.y));
  o.z = __half_as_ushort(__float2half_rn(v.z));
  o.w = __half_as_ushort(__float2half_rn(v.w));
  Xh4[gid] = o;
}

// ---------------- K1: 128x128 X*X^T, DIRECT-FROM-L2, zero K-loop barriers --
// 528 blocks x 256 threads (4 waves, 2x2 wave grid, 64x64 per wave).
// R9 change (single variable): Xh is 4 MB = L2-resident, so LDS staging +
// per-step __syncthreads (vmcnt(0) drain vs ~300cy L2 latency with only
// ~310cy MFMA per step = exposed stall every step; MfmaUtil never above 7%)
// is replaced by per-lane global fragment loads. L2 traffic 270 MB @ 34.5
// TB/s = 7.8 us; MFMA floor 4.3 us. No inter-wave sharing -> no barriers ->
// compiler schedules per-wave vmcnt freely over a fully-unrolled 2-deep
// register pipeline (its strength, m97 asm). One barrier total (epilogue).
// Fragment addr: row*1KB + q4*16B, 16B-aligned; a wave's load = 16
// contiguous 64B segments (cache-line friendly).
__global__ __launch_bounds__(256, 3) void gemm_stats_kernel(
    const _Float16* __restrict__ Xh, const int* __restrict__ tgt,
    float* __restrict__ slots, float* __restrict__ top10g) {
  __shared__ int tA[128], tB[128];
  __shared__ float redf[2][4];
  __shared__ unsigned redu[4];
  __shared__ float redm[4];
  __shared__ unsigned redc[4];
  __shared__ float cbuf[CCAP];
  __shared__ unsigned ccnt;
  __shared__ unsigned scc;

  int tid = threadIdx.x;
  if (tid == 0) ccnt = 0u;  // visible after the epilogue barrier

  // decode upper-triangle tile (br <= bc)
  int id = blockIdx.x, br = 0;
  while (id >= (NT - br)) { id -= (NT - br); br++; }
  int bc = br + id;

  if (tid < 128) tA[tid] = tgt[br * 128 + tid];
  else tB[tid - 128] = tgt[bc * 128 + (tid - 128)];

  int lane = tid & 63, wave = tid >> 6;
  int wm2 = (wave >> 1) << 6;  // 0 or 64: wave row-half
  int wn2 = (wave & 1) << 6;   // 0 or 64: wave col-half
  int lrow = lane & 15;
  int q4 = lane >> 4;          // k-chunk 0..3 (8 f16 each)
  int quad4 = q4 * 4;

  // per-lane fragment base pointers (A rows and B rows of this wave's tile)
  const _Float16* pA[4];
  const _Float16* pB[4];
#pragma unroll
  for (int mi = 0; mi < 4; mi++)
    pA[mi] = Xh + (size_t)(br * 128 + wm2 + mi * 16 + lrow) * D + q4 * 8;
#pragma unroll
  for (int ni = 0; ni < 4; ni++)
    pB[ni] = Xh + (size_t)(bc * 128 + wn2 + ni * 16 + lrow) * D + q4 * 8;

  // diag blocks: wave 2 (rows 64..127 x cols 0..63) is entirely j < i
  bool deadWave = (br == bc) && (wave == 2);

  f32x4 acc[4][4] = {};
  if (!deadWave) {
    f16x8 af[2][4], bf[2][4];
#pragma unroll
    for (int mi = 0; mi < 4; mi++) af[0][mi] = *(const f16x8*)(pA[mi]);
#pragma unroll
    for (int ni = 0; ni < 4; ni++) bf[0][ni] = *(const f16x8*)(pB[ni]);
#pragma unroll
    for (int t = 0; t < 16; t++) {
      const int cur = t & 1;  // compile-time under full unroll (rule #20 ok)
      if (t < 15) {
        int k1 = (t + 1) * 32;
#pragma unroll
        for (int mi = 0; mi < 4; mi++)
          af[cur ^ 1][mi] = *(const f16x8*)(pA[mi] + k1);
#pragma unroll
        for (int ni = 0; ni < 4; ni++)
          bf[cur ^ 1][ni] = *(const f16x8*)(pB[ni] + k1);
      }
#pragma unroll
      for (int mi = 0; mi < 4; mi++)
#pragma unroll
        for (int ni = 0; ni < 4; ni++)
          acc[mi][ni] = __builtin_amdgcn_mfma_f32_16x16x32_f16(
              af[cur][mi], bf[cur][ni], acc[mi][ni], 0, 0, 0);
    }
  }
  __syncthreads();  // tA/tB + ccnt=0 visible (the ONLY pre-epilogue barrier)

  // ---- epilogue (R8's, unchanged) ----
  int tj[4];
#pragma unroll
  for (int ni = 0; ni < 4; ni++) tj[ni] = tB[wn2 + ni * 16 + lrow];
  int ib = br * 128 + wm2 + quad4;
  int jb = bc * 128 + wn2 + lrow;

  // shared loss visitor (bit-identical across all passes: same acc, same ops)
  auto forEachLoss = [&](auto&& fn) {
#pragma unroll
    for (int mi = 0; mi < 4; mi++) {
#pragma unroll
      for (int r = 0; r < 4; r++) {
        int trow = tA[wm2 + mi * 16 + quad4 + r];
        int i = ib + mi * 16 + r;
#pragma unroll
        for (int ni = 0; ni < 4; ni++) {
          float s = acc[mi][ni][r];
          int j = jb + ni * 16;
          bool valid = j > i;  // strict upper triangle; doubled at the end
          bool pos = valid && (trow == tj[ni]);
          float loss = fmaxf(0.5f + (pos ? -s : s), 0.0f);
          fn(s, loss, valid, pos);
        }
      }
    }
  };

  // pass 1: stats + per-thread candidate buffer (4 regs; overflow -> atomic)
  float lsv = 0.f, lsp = 0.f, tmax = SENT;
  unsigned cz = 0, cc = 0;
  float b0 = 0.f, b1 = 0.f, b2 = 0.f, b3 = 0.f;
  forEachLoss([&](float s, float loss, bool valid, bool pos) {
    if (valid) {
      lsv += s;
      if (loss == 0.0f) cz += 0x10000u;
      tmax = fmaxf(tmax, loss);
      if (loss >= T0) {
        if (cc == 0) b0 = loss;
        else if (cc == 1) b1 = loss;
        else if (cc == 2) b2 = loss;
        else if (cc == 3) b3 = loss;
        else {  // rare (~0.2/block): direct push
          unsigned op = atomicAdd(&ccnt, 1u);
          if (op < CCAP) cbuf[op] = loss;
        }
        cc++;
      }
    }
    if (pos) { lsp += s; cz += 1u; }
  });

  float lmax = tmax;
#pragma unroll
  for (int o = 32; o > 0; o >>= 1) {
    lsv += __shfl_down(lsv, o);
    lsp += __shfl_down(lsp, o);
    cz += __shfl_down(cz, o);
    lmax = fmaxf(lmax, __shfl_down(lmax, o));
  }
  if (lane == 0) {
    redf[0][wave] = lsv; redf[1][wave] = lsp;
    redu[wave] = cz; redm[wave] = lmax;
  }

  // aggregated candidate append: wave prefix-scan + ONE atomic per wave
  unsigned cnt4 = cc < 4u ? cc : 4u;
  unsigned inc = cnt4;
#pragma unroll
  for (int o = 1; o < 64; o <<= 1) {
    unsigned tt = __shfl_up(inc, o);
    if (lane >= o) inc += tt;
  }
  unsigned base = 0;
  if (lane == 63) base = atomicAdd(&ccnt, inc);  // inc@63 = wave total
  base = __shfl(base, 63);
  unsigned p = base + inc - cnt4;  // exclusive prefix
  if (cnt4 > 0u && p < CCAP) cbuf[p] = b0;
  if (cnt4 > 1u && p + 1 < CCAP) cbuf[p + 1] = b1;
  if (cnt4 > 2u && p + 2 < CCAP) cbuf[p + 2] = b2;
  if (cnt4 > 3u && p + 3 < CCAP) cbuf[p + 3] = b3;
  __syncthreads();  // ccnt final; redf/redu/redm visible

  if (tid == 192) {  // wave 3 lane 0: stats + bmax store (overlaps selection)
    float a = redf[0][0] + redf[0][1] + redf[0][2] + redf[0][3];
    float b = redf[1][0] + redf[1][1] + redf[1][2] + redf[1][3];
    unsigned c = redu[0] + redu[1] + redu[2] + redu[3];
    float bm = fmaxf(fmaxf(redm[0], redm[1]), fmaxf(redm[2], redm[3]));
    slots[blockIdx.x] = a;
    slots[NBLK + blockIdx.x] = b;
    ((unsigned*)slots)[2 * NBLK + blockIdx.x] = c;
    slots[BMAX_IDX + blockIdx.x] = bm;
  }

  unsigned cct = ccnt;  // block-uniform
  if (cct < 10u || cct > CCAP) {
    // exact array-free fallback (pathological data only): binary search the
    // largest threshold Tq (float-bit space; losses >= 0 so bit order ==
    // value order) with count(loss >= Tq) >= 10. Then top-10 = all values
    // > Tq (m <= 9 of them) plus (10-m) copies of Tq.
    unsigned lo = 0u, hi = 0x7f800000u;  // [0.0, +inf)
    while (hi - lo > 1u) {
      unsigned mid = lo + (hi - lo) / 2u;
      float Tm = __uint_as_float(mid);
      unsigned c = 0;
      forEachLoss([&](float s, float loss, bool valid, bool pos) {
        (void)s; (void)pos;
        if (valid && loss >= Tm) c++;
      });
#pragma unroll
      for (int o = 32; o > 0; o >>= 1) c += __shfl_down(c, o);
      if (lane == 0) redc[wave] = c;
      __syncthreads();
      if (tid == 0) scc = redc[0] + redc[1] + redc[2] + redc[3];
      __syncthreads();
      if (scc >= 10u) lo = mid; else hi = mid;
    }
    float Tq = __uint_as_float(lo);
    if (tid == 0) ccnt = 0u;
    __syncthreads();
    forEachLoss([&](float s, float loss, bool valid, bool pos) {
      (void)s; (void)pos;
      if (valid && loss > Tq) {  // strictly greater: m <= 9 values
        unsigned op = atomicAdd(&ccnt, 1u);
        if (op < CCAP) cbuf[op] = loss;
      }
    });
    __syncthreads();
    unsigned m = ccnt;  // <= 9 by search invariant
    if (tid < 10) cbuf[m + tid] = Tq;  // pad to exact top-10 multiset
    __syncthreads();
    cct = m + 10u;
  }

  // block top-10 == top-10 of cbuf (all block-top-10 values are >= T0 when
  // cct in range; fallback normalizes cbuf to a superset otherwise)
  if (wave == 0) {
    float m5[5];
#pragma unroll
    for (int k = 0; k < 5; k++) {
      unsigned g = lane + k * 64u;
      m5[k] = (g < cct) ? cbuf[g] : SENT;
    }
    float b10[10];
    wave_sel10<5>(m5, b10);
    if (lane == 0) {
#pragma unroll
      for (int r = 0; r < 10; r++) top10g[blockIdx.x * 10 + r] = b10[r];
    }
  }
}

// ---------------- K2: ONE-block finalize with block-max prune --------------
// T = 10th-largest block-max => every global-top-10 value lives in a block
// with bmax >= T (>=10 such blocks by ties). Gather only those ~10-16 lists
// (~160 values) instead of merging all 5280. Full-merge fallback if >64
// blocks tie past T. (R7-verified, ~10 us.)
__global__ __launch_bounds__(1024) void finalize_kernel(
    const float* __restrict__ slots, const float* __restrict__ top10g,
    float* __restrict__ out) {
  __shared__ float wml[160];
  __shared__ float redf[2][16];
  __shared__ unsigned redu[2][16];
  __shared__ int blist[64];
  __shared__ unsigned bcnt;
  __shared__ float gbuf[640];
  __shared__ float sT;

  int tid = threadIdx.x, lane = tid & 63, wave = tid >> 6;
  if (tid == 0) bcnt = 0u;

  // stats over 528 block rows
  float sv = 0.f, sp = 0.f;
  unsigned cv = 0, zz = 0;
  if (tid < NBLK) {
    sv = slots[tid];
    sp = slots[NBLK + tid];
    unsigned c = ((const unsigned*)slots)[2 * NBLK + tid];
    cv = c & 0xffffu;
    zz = c >> 16;
  }
  float bm = (tid < NBLK) ? slots[BMAX_IDX + tid] : SENT;
#pragma unroll
  for (int o = 32; o > 0; o >>= 1) {
    sv += __shfl_down(sv, o);
    sp += __shfl_down(sp, o);
    cv += __shfl_down(cv, o);
    zz += __shfl_down(zz, o);
  }
  if (lane == 0) {
    redf[0][wave] = sv; redf[1][wave] = sp;
    redu[0][wave] = cv; redu[1][wave] = zz;
  }

  // T = 10th-largest block-max (two-stage sel10 over 528 maxes)
  float v1[1];
  v1[0] = bm;
  float wl[10];
  wave_sel10<1>(v1, wl);
  if (lane == 0) {
#pragma unroll
    for (int r = 0; r < 10; r++) wml[wave * 10 + r] = wl[r];
  }
  __syncthreads();
  if (wave == 0) {
    float m3[3];
#pragma unroll
    for (int k = 0; k < 3; k++) {
      int g = lane + k * 64;
      m3[k] = (g < 160) ? wml[g] : SENT;
    }
    float t10[10];
    wave_sel10<3>(m3, t10);
    if (lane == 0) sT = t10[9];
  }
  __syncthreads();
  float T = sT;

  if (tid < NBLK && bm >= T) {
    unsigned p = atomicAdd(&bcnt, 1u);
    if (p < 64u) blist[p] = tid;
  }
  __syncthreads();
  unsigned nb = bcnt;  // >= 10 by construction

  float f10[10];
  if (nb <= 64u) {
    // prune path: gather nb lists (<= 640 values), one-wave selection
    unsigned ng = nb * 10u;
    if ((unsigned)tid < ng)
      gbuf[tid] = top10g[(unsigned)blist[tid / 10u] * 10u + tid % 10u];
    __syncthreads();
    if (wave == 0) {
      float mA[10];
#pragma unroll
      for (int k = 0; k < 10; k++) {
        unsigned g = lane + k * 64u;
        mA[k] = (g < ng) ? gbuf[g] : SENT;
      }
      wave_sel10<10>(mA, f10);
    }
  } else {
    // fallback: full 5280-value merge (R6 path)
    float v6[6];
#pragma unroll
    for (int k = 0; k < 6; k++) {
      int g = tid + k * 1024;
      v6[k] = (g < NBLK * 10) ? top10g[g] : SENT;
    }
    float wl2[10];
    wave_sel10<6>(v6, wl2);
    if (lane == 0) {
#pragma unroll
      for (int r = 0; r < 10; r++) wml[wave * 10 + r] = wl2[r];
    }
    __syncthreads();
    if (wave == 0) {
      float m3[3];
#pragma unroll
      for (int k = 0; k < 3; k++) {
        int g = lane + k * 64;
        m3[k] = (g < 160) ? wml[g] : SENT;
      }
      wave_sel10<3>(m3, f10);
    }
  }

  if (wave == 0 && lane == 0) {
    float topsum = 0.f;
#pragma unroll
    for (int r = 0; r < 10; r++) topsum += f10[r];
    float tsv = 0.f, tsp = 0.f;
    unsigned tcv = 0, tzz = 0;
#pragma unroll
    for (int w = 0; w < 16; w++) {
      tsv += redf[0][w]; tsp += redf[1][w];
      tcv += redu[0][w]; tzz += redu[1][w];
    }
    // full-matrix multiset = upper-triangle doubled: top-20 mean == top-10
    // mean; counts double in numerator and denominator (cancel in means)
    out[0] = topsum * 0.1f;
    out[1] = (float)(2u * tzz);
    out[2] = tsp / (float)tcv;
    out[3] = (tsv - tsp) / (float)(TCV - tcv);
  }
}

extern "C" void kernel_launch(void* const* d_in, const int* in_sizes, int n_in,
                              void* d_out, int out_size, void* d_ws,
                              size_t ws_size, hipStream_t stream) {
  const float* X = (const float*)d_in[0];
  const int* tgt = (const int*)d_in[1];
  float* out = (float*)d_out;
  char* ws = (char*)d_ws;

  float* slots = (float*)ws;
  float* top10g = slots + TOP10G_IDX;
  _Float16* Xh = (_Float16*)(ws + XH_OFF);

  prep_kernel<<<(N * D / 4) / 256, 256, 0, stream>>>((const float4*)X,
                                                     (ushort4*)Xh);
  gemm_stats_kernel<<<NBLK, 256, 0, stream>>>(Xh, tgt, slots, top10g);
  finalize_kernel<<<1, 1024, 0, stream>>>(slots, top10g, out);
}

// Round 10
// 104.416 us; speedup vs baseline: 1.2365x; 1.2365x over previous
//
#include <hip/hip_runtime.h>
#include <hip/hip_fp16.h>

// Problem constants (fixed by the reference setup)
constexpr int N = 4096;
constexpr int D = 512;
constexpr int NT = 32;                   // 4096 / 128 tile-rows
constexpr int NBLK = NT * (NT + 1) / 2;  // 528 upper-triangle tiles
constexpr float SENT = -1e30f;           // sentinel (invalid sites / empty slots)
constexpr unsigned TCV = 8386560u;       // N*(N-1)/2 valid strict-upper pairs

// Prefilter threshold: sims ~ N(0, 1/512); loss >= 0.60 <=> ~2.26 sigma =>
// ~194 candidates per full 128x128 block, ~97 per diagonal block. CCAP=320
// is +9 sigma. Exactness NEVER depends on T0: out-of-range counts take the
// exact binary-search fallback below.
constexpr float T0 = 0.60f;
constexpr unsigned CCAP = 320;

typedef _Float16 f16x8 __attribute__((ext_vector_type(8)));
typedef float f32x4 __attribute__((ext_vector_type(4)));

// Exact wave top-10 by repeated selection over per-lane register candidates.
// out[r] ends up wave-uniform. Duplicates preserved (leader pops ONE copy).
// NOTE: mutates vals[] on leader lanes.
template <int M>
__device__ __forceinline__ void wave_sel10(float (&vals)[M], float (&out)[10]) {
  int lane = threadIdx.x & 63;
  float lm = vals[0];
#pragma unroll
  for (int k = 1; k < M; k++) lm = fmaxf(lm, vals[k]);
#pragma unroll
  for (int r = 0; r < 10; r++) {
    float wmx = lm;
#pragma unroll
    for (int ofs = 1; ofs < 64; ofs <<= 1)
      wmx = fmaxf(wmx, __shfl_xor(wmx, ofs));
    out[r] = wmx;
    unsigned long long b = __ballot(lm == wmx);
    int leader = __ffsll(b) - 1;
    if (lane == leader) {
      bool found = false;
#pragma unroll
      for (int k = 0; k < M; k++) {
        bool hit = !found && (vals[k] == wmx);
        vals[k] = hit ? SENT : vals[k];
        found = found || hit;
      }
      lm = vals[0];
#pragma unroll
      for (int k = 1; k < M; k++) lm = fmaxf(lm, vals[k]);
    }
  }
}

// ws layout (float indices unless noted):
//   [0, 528)       f32 blk_sumv
//   [528, 1056)    f32 blk_sump
//   [1056, 1584)   u32 cntpack  (cntp | zeros<<16; per-block totals <= 16384)
//   [1584, 2112)   f32 bmax[528]       per-block max loss (finalize prune)
//   [2112, 7392)   f32 top10g[528*10]
//   byte 32768:    f16 Xt[N*D]  in FRAGMENT-TILED layout (see prep)
constexpr int BMAX_IDX = 3 * NBLK;
constexpr int TOP10G_IDX = 4 * NBLK;
constexpr int XH_OFF = 32768;

// ---------------- K0: fp32 -> f16 convert into FRAGMENT-TILED layout -------
// Subtile (rg, kc) = rows rg*16..+15 x f16-cols kc*32..+31, stored as 64
// lanes x 8 f16 in MFMA lane order: lane = (row&15) + 16*q4, q4 = (k/8)&3.
// Elem offset of slot: ((rg*16 + kc)*64 + lane)*8  (16B per lane slot).
// => a wave's fragment load is ONE contiguous 1KB burst (base + lane*16),
// fixing R9's 16-scattered-lines-per-instruction TA bottleneck.
// Output-indexed: writes perfectly coalesced; reads scatter (L2 absorbs).
__global__ void prep_kernel(const float* __restrict__ X,
                            _Float16* __restrict__ Xt) {
  int g = blockIdx.x * 256 + threadIdx.x;  // one 16B output slot (8 f16)
  int lane = g & 63;
  int kc = (g >> 6) & 15;
  int rg = g >> 10;
  int row = rg * 16 + (lane & 15);
  int k0 = kc * 32 + (lane >> 4) * 8;
  const float4* src = (const float4*)(X + (size_t)row * D + k0);
  float4 a = src[0], b = src[1];
  f16x8 o;
  o[0] = (_Float16)a.x; o[1] = (_Float16)a.y;
  o[2] = (_Float16)a.z; o[3] = (_Float16)a.w;
  o[4] = (_Float16)b.x; o[5] = (_Float16)b.y;
  o[6] = (_Float16)b.z; o[7] = (_Float16)b.w;
  *(f16x8*)(Xt + (size_t)g * 8) = o;
}

// ---------------- K1: 128x128 X*X^T, zero-LDS zero-barrier K-loop ----------
// 528 blocks x 256 threads (4 waves, 2x2 wave grid, 64x64 per wave).
// R10 change (single variable vs R9): fragment loads hit the TILED layout,
// so each of the 8 loads/wave/step is one contiguous 1KB dwordx4 burst.
// L2 traffic 270 MB @ 34.5 TB/s = 7.8 us; MFMA floor 4.3 us. No barriers in
// the K-loop (no inter-wave sharing); compiler schedules per-wave vmcnt over
// the fully-unrolled 2-deep register pipeline (compiled clean in R9: 72 VGPR,
// no spill). One barrier total, before the epilogue.
__global__ __launch_bounds__(256, 3) void gemm_stats_kernel(
    const _Float16* __restrict__ Xt, const int* __restrict__ tgt,
    float* __restrict__ slots, float* __restrict__ top10g) {
  __shared__ int tA[128], tB[128];
  __shared__ float redf[2][4];
  __shared__ unsigned redu[4];
  __shared__ float redm[4];
  __shared__ unsigned redc[4];
  __shared__ float cbuf[CCAP];
  __shared__ unsigned ccnt;
  __shared__ unsigned scc;

  int tid = threadIdx.x;
  if (tid == 0) ccnt = 0u;  // visible after the epilogue barrier

  // decode upper-triangle tile (br <= bc)
  int id = blockIdx.x, br = 0;
  while (id >= (NT - br)) { id -= (NT - br); br++; }
  int bc = br + id;

  if (tid < 128) tA[tid] = tgt[br * 128 + tid];
  else tB[tid - 128] = tgt[bc * 128 + (tid - 128)];

  int lane = tid & 63, wave = tid >> 6;
  int wm2 = (wave >> 1) << 6;  // 0 or 64: wave row-half
  int wn2 = (wave & 1) << 6;   // 0 or 64: wave col-half
  int lrow = lane & 15;
  int q4 = lane >> 4;
  int quad4 = q4 * 4;

  // tiled-layout fragment bases: subtile (rg, t) at elem rg*8192 + t*512,
  // lane slot at +lane*8. rg_A = br*8 + (wave>>1)*4 + mi; rg_B likewise.
  int rgA = br * 8 + (wave >> 1) * 4;
  int rgB = bc * 8 + (wave & 1) * 4;
  const _Float16* pA = Xt + (size_t)rgA * 8192 + lane * 8;
  const _Float16* pB = Xt + (size_t)rgB * 8192 + lane * 8;

  // diag blocks: wave 2 (rows 64..127 x cols 0..63) is entirely j < i
  bool deadWave = (br == bc) && (wave == 2);

  f32x4 acc[4][4] = {};
  if (!deadWave) {
    f16x8 af[2][4], bf[2][4];
#pragma unroll
    for (int mi = 0; mi < 4; mi++)
      af[0][mi] = *(const f16x8*)(pA + mi * 8192);
#pragma unroll
    for (int ni = 0; ni < 4; ni++)
      bf[0][ni] = *(const f16x8*)(pB + ni * 8192);
#pragma unroll
    for (int t = 0; t < 16; t++) {
      const int cur = t & 1;  // compile-time under full unroll (rule #20 ok)
      if (t < 15) {
        int k1 = (t + 1) * 512;
#pragma unroll
        for (int mi = 0; mi < 4; mi++)
          af[cur ^ 1][mi] = *(const f16x8*)(pA + mi * 8192 + k1);
#pragma unroll
        for (int ni = 0; ni < 4; ni++)
          bf[cur ^ 1][ni] = *(const f16x8*)(pB + ni * 8192 + k1);
      }
#pragma unroll
      for (int mi = 0; mi < 4; mi++)
#pragma unroll
        for (int ni = 0; ni < 4; ni++)
          acc[mi][ni] = __builtin_amdgcn_mfma_f32_16x16x32_f16(
              af[cur][mi], bf[cur][ni], acc[mi][ni], 0, 0, 0);
    }
  }
  __syncthreads();  // tA/tB + ccnt=0 visible (the ONLY pre-epilogue barrier)

  // ---- epilogue (R8's, unchanged) ----
  int tj[4];
#pragma unroll
  for (int ni = 0; ni < 4; ni++) tj[ni] = tB[wn2 + ni * 16 + lrow];
  int ib = br * 128 + wm2 + quad4;
  int jb = bc * 128 + wn2 + lrow;

  // shared loss visitor (bit-identical across all passes: same acc, same ops)
  auto forEachLoss = [&](auto&& fn) {
#pragma unroll
    for (int mi = 0; mi < 4; mi++) {
#pragma unroll
      for (int r = 0; r < 4; r++) {
        int trow = tA[wm2 + mi * 16 + quad4 + r];
        int i = ib + mi * 16 + r;
#pragma unroll
        for (int ni = 0; ni < 4; ni++) {
          float s = acc[mi][ni][r];
          int j = jb + ni * 16;
          bool valid = j > i;  // strict upper triangle; doubled at the end
          bool pos = valid && (trow == tj[ni]);
          float loss = fmaxf(0.5f + (pos ? -s : s), 0.0f);
          fn(s, loss, valid, pos);
        }
      }
    }
  };

  // pass 1: stats + per-thread candidate buffer (4 regs; overflow -> atomic)
  float lsv = 0.f, lsp = 0.f, tmax = SENT;
  unsigned cz = 0, cc = 0;
  float b0 = 0.f, b1 = 0.f, b2 = 0.f, b3 = 0.f;
  forEachLoss([&](float s, float loss, bool valid, bool pos) {
    if (valid) {
      lsv += s;
      if (loss == 0.0f) cz += 0x10000u;
      tmax = fmaxf(tmax, loss);
      if (loss >= T0) {
        if (cc == 0) b0 = loss;
        else if (cc == 1) b1 = loss;
        else if (cc == 2) b2 = loss;
        else if (cc == 3) b3 = loss;
        else {  // rare (~0.2/block): direct push
          unsigned op = atomicAdd(&ccnt, 1u);
          if (op < CCAP) cbuf[op] = loss;
        }
        cc++;
      }
    }
    if (pos) { lsp += s; cz += 1u; }
  });

  float lmax = tmax;
#pragma unroll
  for (int o = 32; o > 0; o >>= 1) {
    lsv += __shfl_down(lsv, o);
    lsp += __shfl_down(lsp, o);
    cz += __shfl_down(cz, o);
    lmax = fmaxf(lmax, __shfl_down(lmax, o));
  }
  if (lane == 0) {
    redf[0][wave] = lsv; redf[1][wave] = lsp;
    redu[wave] = cz; redm[wave] = lmax;
  }

  // aggregated candidate append: wave prefix-scan + ONE atomic per wave
  unsigned cnt4 = cc < 4u ? cc : 4u;
  unsigned inc = cnt4;
#pragma unroll
  for (int o = 1; o < 64; o <<= 1) {
    unsigned tt = __shfl_up(inc, o);
    if (lane >= o) inc += tt;
  }
  unsigned base = 0;
  if (lane == 63) base = atomicAdd(&ccnt, inc);  // inc@63 = wave total
  base = __shfl(base, 63);
  unsigned p = base + inc - cnt4;  // exclusive prefix
  if (cnt4 > 0u && p < CCAP) cbuf[p] = b0;
  if (cnt4 > 1u && p + 1 < CCAP) cbuf[p + 1] = b1;
  if (cnt4 > 2u && p + 2 < CCAP) cbuf[p + 2] = b2;
  if (cnt4 > 3u && p + 3 < CCAP) cbuf[p + 3] = b3;
  __syncthreads();  // ccnt final; redf/redu/redm visible

  if (tid == 192) {  // wave 3 lane 0: stats + bmax store (overlaps selection)
    float a = redf[0][0] + redf[0][1] + redf[0][2] + redf[0][3];
    float b = redf[1][0] + redf[1][1] + redf[1][2] + redf[1][3];
    unsigned c = redu[0] + redu[1] + redu[2] + redu[3];
    float bm = fmaxf(fmaxf(redm[0], redm[1]), fmaxf(redm[2], redm[3]));
    slots[blockIdx.x] = a;
    slots[NBLK + blockIdx.x] = b;
    ((unsigned*)slots)[2 * NBLK + blockIdx.x] = c;
    slots[BMAX_IDX + blockIdx.x] = bm;
  }

  unsigned cct = ccnt;  // block-uniform
  if (cct < 10u || cct > CCAP) {
    // exact array-free fallback (pathological data only): binary search the
    // largest threshold Tq (float-bit space; losses >= 0 so bit order ==
    // value order) with count(loss >= Tq) >= 10. Then top-10 = all values
    // > Tq (m <= 9 of them) plus (10-m) copies of Tq.
    unsigned lo = 0u, hi = 0x7f800000u;  // [0.0, +inf)
    while (hi - lo > 1u) {
      unsigned mid = lo + (hi - lo) / 2u;
      float Tm = __uint_as_float(mid);
      unsigned c = 0;
      forEachLoss([&](float s, float loss, bool valid, bool pos) {
        (void)s; (void)pos;
        if (valid && loss >= Tm) c++;
      });
#pragma unroll
      for (int o = 32; o > 0; o >>= 1) c += __shfl_down(c, o);
      if (lane == 0) redc[wave] = c;
      __syncthreads();
      if (tid == 0) scc = redc[0] + redc[1] + redc[2] + redc[3];
      __syncthreads();
      if (scc >= 10u) lo = mid; else hi = mid;
    }
    float Tq = __uint_as_float(lo);
    if (tid == 0) ccnt = 0u;
    __syncthreads();
    forEachLoss([&](float s, float loss, bool valid, bool pos) {
      (void)s; (void)pos;
      if (valid && loss > Tq) {  // strictly greater: m <= 9 values
        unsigned op = atomicAdd(&ccnt, 1u);
        if (op < CCAP) cbuf[op] = loss;
      }
    });
    __syncthreads();
    unsigned m = ccnt;  // <= 9 by search invariant
    if (tid < 10) cbuf[m + tid] = Tq;  // pad to exact top-10 multiset
    __syncthreads();
    cct = m + 10u;
  }

  // block top-10 == top-10 of cbuf (all block-top-10 values are >= T0 when
  // cct in range; fallback normalizes cbuf to a superset otherwise)
  if (wave == 0) {
    float m5[5];
#pragma unroll
    for (int k = 0; k < 5; k++) {
      unsigned g = lane + k * 64u;
      m5[k] = (g < cct) ? cbuf[g] : SENT;
    }
    float b10[10];
    wave_sel10<5>(m5, b10);
    if (lane == 0) {
#pragma unroll
      for (int r = 0; r < 10; r++) top10g[blockIdx.x * 10 + r] = b10[r];
    }
  }
}

// ---------------- K2: ONE-block finalize with block-max prune --------------
// T = 10th-largest block-max => every global-top-10 value lives in a block
// with bmax >= T (>=10 such blocks by ties). Gather only those ~10-16 lists
// (~160 values) instead of merging all 5280. Full-merge fallback if >64
// blocks tie past T.
__global__ __launch_bounds__(1024) void finalize_kernel(
    const float* __restrict__ slots, const float* __restrict__ top10g,
    float* __restrict__ out) {
  __shared__ float wml[160];
  __shared__ float redf[2][16];
  __shared__ unsigned redu[2][16];
  __shared__ int blist[64];
  __shared__ unsigned bcnt;
  __shared__ float gbuf[640];
  __shared__ float sT;

  int tid = threadIdx.x, lane = tid & 63, wave = tid >> 6;
  if (tid == 0) bcnt = 0u;

  // stats over 528 block rows
  float sv = 0.f, sp = 0.f;
  unsigned cv = 0, zz = 0;
  if (tid < NBLK) {
    sv = slots[tid];
    sp = slots[NBLK + tid];
    unsigned c = ((const unsigned*)slots)[2 * NBLK + tid];
    cv = c & 0xffffu;
    zz = c >> 16;
  }
  float bm = (tid < NBLK) ? slots[BMAX_IDX + tid] : SENT;
#pragma unroll
  for (int o = 32; o > 0; o >>= 1) {
    sv += __shfl_down(sv, o);
    sp += __shfl_down(sp, o);
    cv += __shfl_down(cv, o);
    zz += __shfl_down(zz, o);
  }
  if (lane == 0) {
    redf[0][wave] = sv; redf[1][wave] = sp;
    redu[0][wave] = cv; redu[1][wave] = zz;
  }

  // T = 10th-largest block-max (two-stage sel10 over 528 maxes)
  float v1[1];
  v1[0] = bm;
  float wl[10];
  wave_sel10<1>(v1, wl);
  if (lane == 0) {
#pragma unroll
    for (int r = 0; r < 10; r++) wml[wave * 10 + r] = wl[r];
  }
  __syncthreads();
  if (wave == 0) {
    float m3[3];
#pragma unroll
    for (int k = 0; k < 3; k++) {
      int g = lane + k * 64;
      m3[k] = (g < 160) ? wml[g] : SENT;
    }
    float t10[10];
    wave_sel10<3>(m3, t10);
    if (lane == 0) sT = t10[9];
  }
  __syncthreads();
  float T = sT;

  if (tid < NBLK && bm >= T) {
    unsigned p = atomicAdd(&bcnt, 1u);
    if (p < 64u) blist[p] = tid;
  }
  __syncthreads();
  unsigned nb = bcnt;  // >= 10 by construction

  float f10[10];
  if (nb <= 64u) {
    // prune path: gather nb lists (<= 640 values), one-wave selection
    unsigned ng = nb * 10u;
    if ((unsigned)tid < ng)
      gbuf[tid] = top10g[(unsigned)blist[tid / 10u] * 10u + tid % 10u];
    __syncthreads();
    if (wave == 0) {
      float mA[10];
#pragma unroll
      for (int k = 0; k < 10; k++) {
        unsigned g = lane + k * 64u;
        mA[k] = (g < ng) ? gbuf[g] : SENT;
      }
      wave_sel10<10>(mA, f10);
    }
  } else {
    // fallback: full 5280-value merge
    float v6[6];
#pragma unroll
    for (int k = 0; k < 6; k++) {
      int g = tid + k * 1024;
      v6[k] = (g < NBLK * 10) ? top10g[g] : SENT;
    }
    float wl2[10];
    wave_sel10<6>(v6, wl2);
    if (lane == 0) {
#pragma unroll
      for (int r = 0; r < 10; r++) wml[wave * 10 + r] = wl2[r];
    }
    __syncthreads();
    if (wave == 0) {
      float m3[3];
#pragma unroll
      for (int k = 0; k < 3; k++) {
        int g = lane + k * 64;
        m3[k] = (g < 160) ? wml[g] : SENT;
      }
      wave_sel10<3>(m3, f10);
    }
  }

  if (wave == 0 && lane == 0) {
    float topsum = 0.f;
#pragma unroll
    for (int r = 0; r < 10; r++) topsum += f10[r];
    float tsv = 0.f, tsp = 0.f;
    unsigned tcv = 0, tzz = 0;
#pragma unroll
    for (int w = 0; w < 16; w++) {
      tsv += redf[0][w]; tsp += redf[1][w];
      tcv += redu[0][w]; tzz += redu[1][w];
    }
    // full-matrix multiset = upper-triangle doubled: top-20 mean == top-10
    // mean; counts double in numerator and denominator (cancel in means)
    out[0] = topsum * 0.1f;
    out[1] = (float)(2u * tzz);
    out[2] = tsp / (float)tcv;
    out[3] = (tsv - tsp) / (float)(TCV - tcv);
  }
}

extern "C" void kernel_launch(void* const* d_in, const int* in_sizes, int n_in,
                              void* d_out, int out_size, void* d_ws,
                              size_t ws_size, hipStream_t stream) {
  const float* X = (const float*)d_in[0];
  const int* tgt = (const int*)d_in[1];
  float* out = (float*)d_out;
  char* ws = (char*)d_ws;

  float* slots = (float*)ws;
  float* top10g = slots + TOP10G_IDX;
  _Float16* Xt = (_Float16*)(ws + XH_OFF);

  prep_kernel<<<(N * D / 8) / 256, 256, 0, stream>>>(X, Xt);
  gemm_stats_kernel<<<NBLK, 256, 0, stream>>>(Xt, tgt, slots, top10g);
  finalize_kernel<<<1, 1024, 0, stream>>>(slots, top10g, out);
}

// Round 11
// 100.504 us; speedup vs baseline: 1.2847x; 1.0389x over previous
//
#include <hip/hip_runtime.h>
#include <hip/hip_fp16.h>

// Problem constants (fixed by the reference setup)
constexpr int N = 4096;
constexpr int D = 512;
constexpr int NT = 32;                   // 4096 / 128 tile-rows
constexpr int NBLK = NT * (NT + 1) / 2;  // 528 upper-triangle tiles
constexpr float SENT = -1e30f;           // sentinel (invalid sites / empty slots)
constexpr unsigned TCV = 8386560u;       // N*(N-1)/2 valid strict-upper pairs

// Per-block candidate prefilter threshold. sims ~ N(0, 1/512); loss >= 0.60
// <=> s >= 0.10 (2.26 sigma) => ~194 candidates per full 128x128 block,
// ~97 per diagonal block. CCAP=320 is +9 sigma vs 194. Exactness NEVER
// depends on T0: blocks with cnt<10 or cnt>CCAP take the exact fallback.
constexpr float T0 = 0.60f;
constexpr unsigned CCAP = 320;

typedef _Float16 f16x8 __attribute__((ext_vector_type(8)));
typedef float f32x4 __attribute__((ext_vector_type(4)));

// async 16B/lane global->LDS (wave-uniform LDS base + lane*16)
__device__ __forceinline__ void load_lds16(const _Float16* g, _Float16* l) {
  __builtin_amdgcn_global_load_lds(
      (const __attribute__((address_space(1))) void*)g,
      (__attribute__((address_space(3))) void*)l, 16, 0, 0);
}

// Exact wave top-10 by repeated selection over per-lane register candidates.
// out[r] ends up wave-uniform. Duplicates preserved (leader pops ONE copy).
// NOTE: mutates vals[] on leader lanes.
template <int M>
__device__ __forceinline__ void wave_sel10(float (&vals)[M], float (&out)[10]) {
  int lane = threadIdx.x & 63;
  float lm = vals[0];
#pragma unroll
  for (int k = 1; k < M; k++) lm = fmaxf(lm, vals[k]);
#pragma unroll
  for (int r = 0; r < 10; r++) {
    float wmx = lm;
#pragma unroll
    for (int ofs = 1; ofs < 64; ofs <<= 1)
      wmx = fmaxf(wmx, __shfl_xor(wmx, ofs));
    out[r] = wmx;
    unsigned long long b = __ballot(lm == wmx);
    int leader = __ffsll(b) - 1;
    if (lane == leader) {
      bool found = false;
#pragma unroll
      for (int k = 0; k < M; k++) {
        bool hit = !found && (vals[k] == wmx);
        vals[k] = hit ? SENT : vals[k];
        found = found || hit;
      }
      lm = vals[0];
#pragma unroll
      for (int k = 1; k < M; k++) lm = fmaxf(lm, vals[k]);
    }
  }
}

// ws layout (float indices unless noted):
//   [0, 528)       f32 blk_sumv
//   [528, 1056)    f32 blk_sump
//   [1056, 1584)   u32 cntpack  (cntp | zeros<<16; per-block totals <= 16384)
//   [1584, 2112)   f32 bmax[528]       per-block max loss (finalize prune)
//   [2112, 7392)   f32 top10g[528*10]
//   byte 32768:    f16 Xh[N*D]  (row-major)
constexpr int BMAX_IDX = 3 * NBLK;
constexpr int TOP10G_IDX = 4 * NBLK;
constexpr int XH_OFF = 32768;

// ---------------- K0: fp32 -> f16 convert (R6's, row-major) ----------------
__global__ void prep_kernel(const float4* __restrict__ X4,
                            ushort4* __restrict__ Xh4) {
  int gid = blockIdx.x * 256 + threadIdx.x;  // grid exactly N*D/4 threads
  float4 v = X4[gid];
  ushort4 o;
  o.x = __half_as_ushort(__float2half_rn(v.x));
  o.y = __half_as_ushort(__float2half_rn(v.y));
  o.z = __half_as_ushort(__float2half_rn(v.z));
  o.w = __half_as_ushort(__float2half_rn(v.w));
  Xh4[gid] = o;
}

// ---------------- K1: R6's verified gemm (97.5us run) + bmax graft ---------
// 528 blocks x 256 threads (4 waves, 2x2 wave grid, 64x64 per wave), BK=32,
// 2-buf LDS + one __syncthreads per K-step (the compiler places the single
// vmcnt drain at the barrier; asm grafts regress — R7). LDS-atomic prefilter
// epilogue exactly as in the 97.5us run. ONLY additions vs R6: track per-
// block max loss (1 fmaxf/iter in the existing loop + 1 lane in the existing
// shuffle reduce + 1 store) to feed the pruned finalize.
// Swizzle (verified R6): LDS pos p of row r holds chunk p^((r>>1)&3);
// read key (lrow>>1)&3 is wave-invariant (row bases multiples of 16).
__global__ __launch_bounds__(256, 3) void gemm_stats_kernel(
    const _Float16* __restrict__ Xh, const int* __restrict__ tgt,
    float* __restrict__ slots, float* __restrict__ top10g) {
  __shared__ _Float16 As[2][128 * 32];  // 2 x 8 KB
  __shared__ _Float16 Bs[2][128 * 32];  // 2 x 8 KB
  __shared__ int tA[128], tB[128];
  __shared__ float redf[2][4];
  __shared__ unsigned redu[4];
  __shared__ float redm[4];
  __shared__ float wml[40];  // fallback only
  __shared__ float cbuf[CCAP];
  __shared__ unsigned ccnt;

  int tid = threadIdx.x;
  if (tid == 0) ccnt = 0u;  // visible after first K-loop barrier

  // decode upper-triangle tile (br <= bc)
  int id = blockIdx.x, br = 0;
  while (id >= (NT - br)) { id -= (NT - br); br++; }
  int bc = br + id;

  if (tid < 128) tA[tid] = tgt[br * 128 + tid];
  else tB[tid - 128] = tgt[bc * 128 + (tid - 128)];

  int lane = tid & 63, wave = tid >> 6;
  int wm2 = (wave >> 1) << 6;  // 0 or 64: wave row-half
  int wn2 = (wave & 1) << 6;   // 0 or 64: wave col-half
  int lrow = lane & 15;
  int q4 = lane >> 4;          // k-chunk 0..3 (8 f16 each)
  int xk = (lrow >> 1) & 3;    // 32-col swizzle key
  int quad4 = q4 * 4;

  // staging: 512 16B chunks per matrix per K-step; issue i covers
  // C = i*256 + tid; row=C>>2, pos p=C&3 holds global chunk p^((row>>1)&3)
  int srow[2], scol[2], sdst[2];
#pragma unroll
  for (int i = 0; i < 2; i++) {
    int C = i * 256 + tid;
    int row = C >> 2, p = C & 3;
    srow[i] = row;
    scol[i] = (p ^ ((row >> 1) & 3)) * 8;
    sdst[i] = (i * 4 + wave) * 512;  // wave-uniform elem base (+lane*8 by HW)
  }
  const _Float16* Arow = Xh + (size_t)(br * 128) * D;
  const _Float16* Brow = Xh + (size_t)(bc * 128) * D;

  // prologue: stage k0=0 into buffer 0
#pragma unroll
  for (int i = 0; i < 2; i++) {
    load_lds16(Arow + srow[i] * D + scol[i], &As[0][sdst[i]]);
    load_lds16(Brow + srow[i] * D + scol[i], &Bs[0][sdst[i]]);
  }

  f32x4 acc[4][4] = {};
#pragma unroll
  for (int t = 0; t < 16; t++) {
    int cur = t & 1;
    __syncthreads();  // drains vmcnt: buf[cur] visible; buf[cur^1] free
    if (t < 15) {
      int k0 = (t + 1) * 32;
#pragma unroll
      for (int i = 0; i < 2; i++) {
        load_lds16(Arow + srow[i] * D + k0 + scol[i], &As[cur ^ 1][sdst[i]]);
        load_lds16(Brow + srow[i] * D + k0 + scol[i], &Bs[cur ^ 1][sdst[i]]);
      }
    }
    f16x8 af[4], bf[4];
#pragma unroll
    for (int mi = 0; mi < 4; mi++)
      af[mi] = *(const f16x8*)&As[cur][(wm2 + mi * 16 + lrow) * 32 +
                                       (q4 ^ xk) * 8];
#pragma unroll
    for (int ni = 0; ni < 4; ni++)
      bf[ni] = *(const f16x8*)&Bs[cur][(wn2 + ni * 16 + lrow) * 32 +
                                       (q4 ^ xk) * 8];
#pragma unroll
    for (int mi = 0; mi < 4; mi++)
#pragma unroll
      for (int ni = 0; ni < 4; ni++)
        acc[mi][ni] = __builtin_amdgcn_mfma_f32_16x16x32_f16(
            af[mi], bf[ni], acc[mi][ni], 0, 0, 0);
  }

  // ---- epilogue: stats + LDS-atomic candidate prefilter (R6's, + tmax) ----
  int tj[4];
#pragma unroll
  for (int ni = 0; ni < 4; ni++) tj[ni] = tB[wn2 + ni * 16 + lrow];

  float lsv = 0.f, lsp = 0.f, tmax = SENT;
  unsigned cz = 0;  // cntp | zeros<<16 (block totals <= 16384 each)
  int ib = br * 128 + wm2 + quad4;
  int jb = bc * 128 + wn2 + lrow;
#pragma unroll
  for (int mi = 0; mi < 4; mi++) {
#pragma unroll
    for (int r = 0; r < 4; r++) {
      int trow = tA[wm2 + mi * 16 + quad4 + r];
      int i = ib + mi * 16 + r;
#pragma unroll
      for (int ni = 0; ni < 4; ni++) {
        float s = acc[mi][ni][r];
        int j = jb + ni * 16;
        bool valid = j > i;  // strict upper triangle; doubled at the end
        bool pos = valid && (trow == tj[ni]);
        float loss = fmaxf(0.5f + (pos ? -s : s), 0.0f);
        if (valid) {
          lsv += s;
          if (loss == 0.0f) cz += 0x10000u;
          tmax = fmaxf(tmax, loss);
          if (loss >= T0) {  // ~194/block: LDS atomic push
            unsigned p = atomicAdd(&ccnt, 1u);
            if (p < CCAP) cbuf[p] = loss;
          }
        }
        if (pos) { lsp += s; cz += 1u; }
      }
    }
  }
  float lmax = tmax;
#pragma unroll
  for (int o = 32; o > 0; o >>= 1) {
    lsv += __shfl_down(lsv, o);
    lsp += __shfl_down(lsp, o);
    cz += __shfl_down(cz, o);
    lmax = fmaxf(lmax, __shfl_down(lmax, o));
  }
  if (lane == 0) {
    redf[0][wave] = lsv; redf[1][wave] = lsp;
    redu[wave] = cz; redm[wave] = lmax;
  }
  __syncthreads();  // ccnt final; redf/redu/redm visible

  // stats + bmax store on wave 3 (overlaps wave 0's selection)
  if (tid == 192) {
    float a = 0.f, b = 0.f;
    unsigned c = 0;
#pragma unroll
    for (int w = 0; w < 4; w++) { a += redf[0][w]; b += redf[1][w]; c += redu[w]; }
    float bm = fmaxf(fmaxf(redm[0], redm[1]), fmaxf(redm[2], redm[3]));
    slots[blockIdx.x] = a;
    slots[NBLK + blockIdx.x] = b;
    ((unsigned*)slots)[2 * NBLK + blockIdx.x] = c;
    slots[BMAX_IDX + blockIdx.x] = bm;
  }

  unsigned cc = ccnt;  // block-uniform
  if (cc >= 10u && cc <= CCAP) {
    // fast path (always, statistically): block top-10 == top-10 of candidates
    if (wave == 0) {
      float m5[5];
#pragma unroll
      for (int k = 0; k < 5; k++) {
        unsigned g = lane + k * 64u;
        m5[k] = (g < cc) ? cbuf[g] : SENT;
      }
      float b10[10];
      wave_sel10<5>(m5, b10);
      if (lane == 0) {
#pragma unroll
        for (int r = 0; r < 10; r++) top10g[blockIdx.x * 10 + r] = b10[r];
      }
    }
  } else {
    // exact fallback (safety net; ~never taken at T0=0.60): rebuild losses,
    // per-wave selection over 64 regs (scratch OK here), 40 -> 10 merge
    float vals[64];
#pragma unroll
    for (int mi = 0; mi < 4; mi++) {
#pragma unroll
      for (int r = 0; r < 4; r++) {
        int trow = tA[wm2 + mi * 16 + quad4 + r];
        int i = ib + mi * 16 + r;
#pragma unroll
        for (int ni = 0; ni < 4; ni++) {
          float s = acc[mi][ni][r];
          int j = jb + ni * 16;
          bool valid = j > i;
          bool pos = valid && (trow == tj[ni]);
          float loss = fmaxf(0.5f + (pos ? -s : s), 0.0f);
          vals[(mi * 4 + ni) * 4 + r] = valid ? loss : SENT;
        }
      }
    }
    float wl[10];
    wave_sel10<64>(vals, wl);
    if (lane == 0) {
#pragma unroll
      for (int r = 0; r < 10; r++) wml[wave * 10 + r] = wl[r];
    }
    __syncthreads();
    if (wave == 0) {
      float m1[1];
      m1[0] = (lane < 40) ? wml[lane] : SENT;
      float b10[10];
      wave_sel10<1>(m1, b10);
      if (lane == 0) {
#pragma unroll
        for (int r = 0; r < 10; r++) top10g[blockIdx.x * 10 + r] = b10[r];
      }
    }
  }
}

// ---------------- K2: ONE-block finalize with block-max prune --------------
// T = 10th-largest block-max => every global-top-10 value lives in a block
// with bmax >= T (>=10 such blocks by ties). Gather only those ~10-16 lists
// (~160 values) instead of merging all 5280. Full-merge fallback if >64
// blocks tie past T. (R7/R8/R10-verified.)
__global__ __launch_bounds__(1024) void finalize_kernel(
    const float* __restrict__ slots, const float* __restrict__ top10g,
    float* __restrict__ out) {
  __shared__ float wml[160];
  __shared__ float redf[2][16];
  __shared__ unsigned redu[2][16];
  __shared__ int blist[64];
  __shared__ unsigned bcnt;
  __shared__ float gbuf[640];
  __shared__ float sT;

  int tid = threadIdx.x, lane = tid & 63, wave = tid >> 6;
  if (tid == 0) bcnt = 0u;

  // stats over 528 block rows
  float sv = 0.f, sp = 0.f;
  unsigned cv = 0, zz = 0;
  if (tid < NBLK) {
    sv = slots[tid];
    sp = slots[NBLK + tid];
    unsigned c = ((const unsigned*)slots)[2 * NBLK + tid];
    cv = c & 0xffffu;
    zz = c >> 16;
  }
  float bm = (tid < NBLK) ? slots[BMAX_IDX + tid] : SENT;
#pragma unroll
  for (int o = 32; o > 0; o >>= 1) {
    sv += __shfl_down(sv, o);
    sp += __shfl_down(sp, o);
    cv += __shfl_down(cv, o);
    zz += __shfl_down(zz, o);
  }
  if (lane == 0) {
    redf[0][wave] = sv; redf[1][wave] = sp;
    redu[0][wave] = cv; redu[1][wave] = zz;
  }

  // T = 10th-largest block-max (two-stage sel10 over 528 maxes)
  float v1[1];
  v1[0] = bm;
  float wl[10];
  wave_sel10<1>(v1, wl);
  if (lane == 0) {
#pragma unroll
    for (int r = 0; r < 10; r++) wml[wave * 10 + r] = wl[r];
  }
  __syncthreads();
  if (wave == 0) {
    float m3[3];
#pragma unroll
    for (int k = 0; k < 3; k++) {
      int g = lane + k * 64;
      m3[k] = (g < 160) ? wml[g] : SENT;
    }
    float t10[10];
    wave_sel10<3>(m3, t10);
    if (lane == 0) sT = t10[9];
  }
  __syncthreads();
  float T = sT;

  if (tid < NBLK && bm >= T) {
    unsigned p = atomicAdd(&bcnt, 1u);
    if (p < 64u) blist[p] = tid;
  }
  __syncthreads();
  unsigned nb = bcnt;  // >= 10 by construction

  float f10[10];
  if (nb <= 64u) {
    // prune path: gather nb lists (<= 640 values), one-wave selection
    unsigned ng = nb * 10u;
    if ((unsigned)tid < ng)
      gbuf[tid] = top10g[(unsigned)blist[tid / 10u] * 10u + tid % 10u];
    __syncthreads();
    if (wave == 0) {
      float mA[10];
#pragma unroll
      for (int k = 0; k < 10; k++) {
        unsigned g = lane + k * 64u;
        mA[k] = (g < ng) ? gbuf[g] : SENT;
      }
      wave_sel10<10>(mA, f10);
    }
  } else {
    // fallback: full 5280-value merge
    float v6[6];
#pragma unroll
    for (int k = 0; k < 6; k++) {
      int g = tid + k * 1024;
      v6[k] = (g < NBLK * 10) ? top10g[g] : SENT;
    }
    float wl2[10];
    wave_sel10<6>(v6, wl2);
    if (lane == 0) {
#pragma unroll
      for (int r = 0; r < 10; r++) wml[wave * 10 + r] = wl2[r];
    }
    __syncthreads();
    if (wave == 0) {
      float m3[3];
#pragma unroll
      for (int k = 0; k < 3; k++) {
        int g = lane + k * 64;
        m3[k] = (g < 160) ? wml[g] : SENT;
      }
      wave_sel10<3>(m3, f10);
    }
  }

  if (wave == 0 && lane == 0) {
    float topsum = 0.f;
#pragma unroll
    for (int r = 0; r < 10; r++) topsum += f10[r];
    float tsv = 0.f, tsp = 0.f;
    unsigned tcv = 0, tzz = 0;
#pragma unroll
    for (int w = 0; w < 16; w++) {
      tsv += redf[0][w]; tsp += redf[1][w];
      tcv += redu[0][w]; tzz += redu[1][w];
    }
    // full-matrix multiset = upper-triangle doubled: top-20 mean == top-10
    // mean; counts double in numerator and denominator (cancel in means)
    out[0] = topsum * 0.1f;
    out[1] = (float)(2u * tzz);
    out[2] = tsp / (float)tcv;
    out[3] = (tsv - tsp) / (float)(TCV - tcv);
  }
}

extern "C" void kernel_launch(void* const* d_in, const int* in_sizes, int n_in,
                              void* d_out, int out_size, void* d_ws,
                              size_t ws_size, hipStream_t stream) {
  const float* X = (const float*)d_in[0];
  const int* tgt = (const int*)d_in[1];
  float* out = (float*)d_out;
  char* ws = (char*)d_ws;

  float* slots = (float*)ws;
  float* top10g = slots + TOP10G_IDX;
  _Float16* Xh = (_Float16*)(ws + XH_OFF);

  prep_kernel<<<(N * D / 4) / 256, 256, 0, stream>>>((const float4*)X,
                                                     (ushort4*)Xh);
  gemm_stats_kernel<<<NBLK, 256, 0, stream>>>(Xh, tgt, slots, top10g);
  finalize_kernel<<<1, 1024, 0, stream>>>(slots, top10g, out);
}

// Round 12
// 96.310 us; speedup vs baseline: 1.3406x; 1.0435x over previous
//
#include <hip/hip_runtime.h>
#include <hip/hip_fp16.h>

// Problem constants (fixed by the reference setup)
constexpr int N = 4096;
constexpr int D = 512;
constexpr int NT = 32;                   // 4096 / 128 tile-rows
constexpr int NBLK = NT * (NT + 1) / 2;  // 528 upper-triangle tiles
constexpr float SENT = -1e30f;           // sentinel (invalid sites / empty slots)
constexpr unsigned TCV = 8386560u;       // N*(N-1)/2 valid strict-upper pairs

// Per-block candidate prefilter threshold. sims ~ N(0, 1/512); loss >= 0.60
// <=> s >= 0.10 (2.26 sigma) => ~194 candidates per full 128x128 block,
// ~97 per diagonal block. CCAP=320 is +9 sigma vs 194. Exactness NEVER
// depends on T0: blocks with cnt<10 or cnt>CCAP take the exact fallback.
constexpr float T0 = 0.60f;
constexpr unsigned CCAP = 320;

typedef _Float16 f16x8 __attribute__((ext_vector_type(8)));
typedef float f32x4 __attribute__((ext_vector_type(4)));

// async 16B/lane global->LDS (wave-uniform LDS base + lane*16)
__device__ __forceinline__ void load_lds16(const _Float16* g, _Float16* l) {
  __builtin_amdgcn_global_load_lds(
      (const __attribute__((address_space(1))) void*)g,
      (__attribute__((address_space(3))) void*)l, 16, 0, 0);
}

// Exact wave top-10 by repeated selection over per-lane register candidates.
// out[r] ends up wave-uniform. Duplicates preserved (leader pops ONE copy).
// NOTE: mutates vals[] on leader lanes.
template <int M>
__device__ __forceinline__ void wave_sel10(float (&vals)[M], float (&out)[10]) {
  int lane = threadIdx.x & 63;
  float lm = vals[0];
#pragma unroll
  for (int k = 1; k < M; k++) lm = fmaxf(lm, vals[k]);
#pragma unroll
  for (int r = 0; r < 10; r++) {
    float wmx = lm;
#pragma unroll
    for (int ofs = 1; ofs < 64; ofs <<= 1)
      wmx = fmaxf(wmx, __shfl_xor(wmx, ofs));
    out[r] = wmx;
    unsigned long long b = __ballot(lm == wmx);
    int leader = __ffsll(b) - 1;
    if (lane == leader) {
      bool found = false;
#pragma unroll
      for (int k = 0; k < M; k++) {
        bool hit = !found && (vals[k] == wmx);
        vals[k] = hit ? SENT : vals[k];
        found = found || hit;
      }
      lm = vals[0];
#pragma unroll
      for (int k = 1; k < M; k++) lm = fmaxf(lm, vals[k]);
    }
  }
}

// ws layout (float indices unless noted):
//   [0, 528)       f32 blk_sumv
//   [528, 1056)    f32 blk_sump
//   [1056, 1584)   u32 cntpack  (cntp | zeros<<16; per-block totals <= 16384)
//   [1584, 6864)   f32 top10g[528*10]
//   byte 32768:    f16 Xh[N*D]  (row-major)
constexpr int TOP10G_IDX = 1584;
constexpr int XH_OFF = 32768;

// ---------------- K0: fp32 -> f16 convert ----------------
__global__ void prep_kernel(const float4* __restrict__ X4,
                            ushort4* __restrict__ Xh4) {
  int gid = blockIdx.x * 256 + threadIdx.x;  // grid exactly N*D/4 threads
  float4 v = X4[gid];
  ushort4 o;
  o.x = __half_as_ushort(__float2half_rn(v.x));
  o.y = __half_as_ushort(__float2half_rn(v.y));
  o.z = __half_as_ushort(__float2half_rn(v.z));
  o.w = __half_as_ushort(__float2half_rn(v.w));
  Xh4[gid] = o;
}

// ---------------- K1: R6's champion gemm (97.5us run) + 2 micro-opts -------
// 528 blocks x 256 threads (4 waves, 2x2 wave grid, 64x64 per wave), BK=32,
// 2-buf LDS + one __syncthreads per K-step (the compiler places the single
// vmcnt drain at the barrier; every pipelining/direct-load restructure lost
// to this across R7-R10). LDS-atomic prefilter epilogue exactly as the
// 97.5us run. ONLY changes vs R6:
//  (1) XCD work swizzle: work = (bid&7)*66 + (bid>>3) (bijective, 528=8*66).
//      Each XCD gets 66 contiguous triangle tiles -> panel reuse in its L2.
//      Output writes keep blockIdx.x indexing (stats/top10 order-invariant),
//      so a different HW dispatch mapping affects only speed, never results.
//  (2) diag blocks: wave 2 (rows 64..127 x cols 0..63, all j<i) skips
//      frag-read+MFMA (still stages and hits barriers).
// Swizzle (verified R6): LDS pos p of row r holds chunk p^((r>>1)&3);
// read key (lrow>>1)&3 is wave-invariant (row bases multiples of 16).
__global__ __launch_bounds__(256, 3) void gemm_stats_kernel(
    const _Float16* __restrict__ Xh, const int* __restrict__ tgt,
    float* __restrict__ slots, float* __restrict__ top10g) {
  __shared__ _Float16 As[2][128 * 32];  // 2 x 8 KB
  __shared__ _Float16 Bs[2][128 * 32];  // 2 x 8 KB
  __shared__ int tA[128], tB[128];
  __shared__ float redf[2][4];
  __shared__ unsigned redu[4];
  __shared__ float wml[40];  // fallback only
  __shared__ float cbuf[CCAP];
  __shared__ unsigned ccnt;

  int tid = threadIdx.x;
  if (tid == 0) ccnt = 0u;  // visible after first K-loop barrier

  // XCD-aware work swizzle, then decode upper-triangle tile (br <= bc)
  int id = (blockIdx.x & 7) * 66 + (blockIdx.x >> 3);
  int br = 0;
  while (id >= (NT - br)) { id -= (NT - br); br++; }
  int bc = br + id;

  if (tid < 128) tA[tid] = tgt[br * 128 + tid];
  else tB[tid - 128] = tgt[bc * 128 + (tid - 128)];

  int lane = tid & 63, wave = tid >> 6;
  int wm2 = (wave >> 1) << 6;  // 0 or 64: wave row-half
  int wn2 = (wave & 1) << 6;   // 0 or 64: wave col-half
  int lrow = lane & 15;
  int q4 = lane >> 4;          // k-chunk 0..3 (8 f16 each)
  int xk = (lrow >> 1) & 3;    // 32-col swizzle key
  int quad4 = q4 * 4;

  // diag blocks: wave 2 (rows 64..127 x cols 0..63) is entirely j < i
  bool deadWave = (br == bc) && (wave == 2);

  // staging: 512 16B chunks per matrix per K-step; issue i covers
  // C = i*256 + tid; row=C>>2, pos p=C&3 holds global chunk p^((row>>1)&3)
  int srow[2], scol[2], sdst[2];
#pragma unroll
  for (int i = 0; i < 2; i++) {
    int C = i * 256 + tid;
    int row = C >> 2, p = C & 3;
    srow[i] = row;
    scol[i] = (p ^ ((row >> 1) & 3)) * 8;
    sdst[i] = (i * 4 + wave) * 512;  // wave-uniform elem base (+lane*8 by HW)
  }
  const _Float16* Arow = Xh + (size_t)(br * 128) * D;
  const _Float16* Brow = Xh + (size_t)(bc * 128) * D;

  // prologue: stage k0=0 into buffer 0
#pragma unroll
  for (int i = 0; i < 2; i++) {
    load_lds16(Arow + srow[i] * D + scol[i], &As[0][sdst[i]]);
    load_lds16(Brow + srow[i] * D + scol[i], &Bs[0][sdst[i]]);
  }

  f32x4 acc[4][4] = {};
#pragma unroll
  for (int t = 0; t < 16; t++) {
    int cur = t & 1;
    __syncthreads();  // drains vmcnt: buf[cur] visible; buf[cur^1] free
    if (t < 15) {
      int k0 = (t + 1) * 32;
#pragma unroll
      for (int i = 0; i < 2; i++) {
        load_lds16(Arow + srow[i] * D + k0 + scol[i], &As[cur ^ 1][sdst[i]]);
        load_lds16(Brow + srow[i] * D + k0 + scol[i], &Bs[cur ^ 1][sdst[i]]);
      }
    }
    if (!deadWave) {
      f16x8 af[4], bf[4];
#pragma unroll
      for (int mi = 0; mi < 4; mi++)
        af[mi] = *(const f16x8*)&As[cur][(wm2 + mi * 16 + lrow) * 32 +
                                         (q4 ^ xk) * 8];
#pragma unroll
      for (int ni = 0; ni < 4; ni++)
        bf[ni] = *(const f16x8*)&Bs[cur][(wn2 + ni * 16 + lrow) * 32 +
                                         (q4 ^ xk) * 8];
#pragma unroll
      for (int mi = 0; mi < 4; mi++)
#pragma unroll
        for (int ni = 0; ni < 4; ni++)
          acc[mi][ni] = __builtin_amdgcn_mfma_f32_16x16x32_f16(
              af[mi], bf[ni], acc[mi][ni], 0, 0, 0);
    }
  }

  // ---- epilogue: stats + LDS-atomic candidate prefilter (loss inline) ----
  int tj[4];
#pragma unroll
  for (int ni = 0; ni < 4; ni++) tj[ni] = tB[wn2 + ni * 16 + lrow];

  float lsv = 0.f, lsp = 0.f;
  unsigned cz = 0;  // cntp | zeros<<16 (block totals <= 16384 each)
  int ib = br * 128 + wm2 + quad4;
  int jb = bc * 128 + wn2 + lrow;
#pragma unroll
  for (int mi = 0; mi < 4; mi++) {
#pragma unroll
    for (int r = 0; r < 4; r++) {
      int trow = tA[wm2 + mi * 16 + quad4 + r];
      int i = ib + mi * 16 + r;
#pragma unroll
      for (int ni = 0; ni < 4; ni++) {
        float s = acc[mi][ni][r];
        int j = jb + ni * 16;
        bool valid = j > i;  // strict upper triangle; doubled at the end
        bool pos = valid && (trow == tj[ni]);
        float loss = fmaxf(0.5f + (pos ? -s : s), 0.0f);
        if (valid) {
          lsv += s;
          if (loss == 0.0f) cz += 0x10000u;
          if (loss >= T0) {  // ~194/block: LDS atomic push
            unsigned p = atomicAdd(&ccnt, 1u);
            if (p < CCAP) cbuf[p] = loss;
          }
        }
        if (pos) { lsp += s; cz += 1u; }
      }
    }
  }
#pragma unroll
  for (int o = 32; o > 0; o >>= 1) {
    lsv += __shfl_down(lsv, o);
    lsp += __shfl_down(lsp, o);
    cz += __shfl_down(cz, o);
  }
  if (lane == 0) {
    redf[0][wave] = lsv; redf[1][wave] = lsp; redu[wave] = cz;
  }
  __syncthreads();  // ccnt final; redf/redu visible

  // stats store on wave 3 (overlaps wave 0's selection)
  if (tid == 192) {
    float a = 0.f, b = 0.f;
    unsigned c = 0;
#pragma unroll
    for (int w = 0; w < 4; w++) { a += redf[0][w]; b += redf[1][w]; c += redu[w]; }
    slots[blockIdx.x] = a;
    slots[NBLK + blockIdx.x] = b;
    ((unsigned*)slots)[2 * NBLK + blockIdx.x] = c;
  }

  unsigned cc = ccnt;  // block-uniform
  if (cc >= 10u && cc <= CCAP) {
    // fast path (always, statistically): block top-10 == top-10 of candidates
    if (wave == 0) {
      float m5[5];
#pragma unroll
      for (int k = 0; k < 5; k++) {
        unsigned g = lane + k * 64u;
        m5[k] = (g < cc) ? cbuf[g] : SENT;
      }
      float b10[10];
      wave_sel10<5>(m5, b10);
      if (lane == 0) {
#pragma unroll
        for (int r = 0; r < 10; r++) top10g[blockIdx.x * 10 + r] = b10[r];
      }
    }
  } else {
    // exact fallback (safety net; ~never taken at T0=0.60): rebuild losses,
    // per-wave selection over 64 regs (scratch OK here), 40 -> 10 merge
    float vals[64];
#pragma unroll
    for (int mi = 0; mi < 4; mi++) {
#pragma unroll
      for (int r = 0; r < 4; r++) {
        int trow = tA[wm2 + mi * 16 + quad4 + r];
        int i = ib + mi * 16 + r;
#pragma unroll
        for (int ni = 0; ni < 4; ni++) {
          float s = acc[mi][ni][r];
          int j = jb + ni * 16;
          bool valid = j > i;
          bool pos = valid && (trow == tj[ni]);
          float loss = fmaxf(0.5f + (pos ? -s : s), 0.0f);
          vals[(mi * 4 + ni) * 4 + r] = valid ? loss : SENT;
        }
      }
    }
    float wl[10];
    wave_sel10<64>(vals, wl);
    if (lane == 0) {
#pragma unroll
      for (int r = 0; r < 10; r++) wml[wave * 10 + r] = wl[r];
    }
    __syncthreads();
    if (wave == 0) {
      float m1[1];
      m1[0] = (lane < 40) ? wml[lane] : SENT;
      float b10[10];
      wave_sel10<1>(m1, b10);
      if (lane == 0) {
#pragma unroll
        for (int r = 0; r < 10; r++) top10g[blockIdx.x * 10 + r] = b10[r];
      }
    }
  }
}

// ---------------- K2: ONE-block finalize (1024 threads, 16 waves) ----------
// R6's champion version: plain full merge (528 stat rows + 5280-float
// top-10). R8/R11 proved the "pruned" variant's extra serial stages cost
// +3us vs this simple wide merge — fewer sync stages wins at this scale.
__global__ __launch_bounds__(1024) void finalize_kernel(
    const float* __restrict__ slots, const float* __restrict__ top10g,
    float* __restrict__ out) {
  __shared__ float wml[160];
  __shared__ float redf[2][16];
  __shared__ unsigned redu[2][16];

  int tid = threadIdx.x, lane = tid & 63, wave = tid >> 6;

  // stats over 528 block rows (threads 0..527 each load one row)
  float sv = 0.f, sp = 0.f;
  unsigned cv = 0, zz = 0;
  if (tid < NBLK) {
    sv = slots[tid];
    sp = slots[NBLK + tid];
    unsigned c = ((const unsigned*)slots)[2 * NBLK + tid];
    cv = c & 0xffffu;
    zz = c >> 16;
  }

  // top-10 over 5280 floats: 16 waves x 6 regs (covers 6144 slots)
  float v6[6];
#pragma unroll
  for (int k = 0; k < 6; k++) {
    int g = tid + k * 1024;
    v6[k] = (g < NBLK * 10) ? top10g[g] : SENT;
  }

#pragma unroll
  for (int o = 32; o > 0; o >>= 1) {
    sv += __shfl_down(sv, o);
    sp += __shfl_down(sp, o);
    cv += __shfl_down(cv, o);
    zz += __shfl_down(zz, o);
  }
  if (lane == 0) {
    redf[0][wave] = sv; redf[1][wave] = sp;
    redu[0][wave] = cv; redu[1][wave] = zz;
  }

  float wl[10];
  wave_sel10<6>(v6, wl);
  if (lane == 0) {
#pragma unroll
    for (int r = 0; r < 10; r++) wml[wave * 10 + r] = wl[r];
  }
  __syncthreads();

  if (wave == 0) {
    float m3[3];
#pragma unroll
    for (int k = 0; k < 3; k++) {
      int g = lane + k * 64;
      m3[k] = (g < 160) ? wml[g] : SENT;
    }
    float f10[10];
    wave_sel10<3>(m3, f10);
    if (lane == 0) {
      float topsum = 0.f;
#pragma unroll
      for (int r = 0; r < 10; r++) topsum += f10[r];
      float tsv = 0.f, tsp = 0.f;
      unsigned tcv = 0, tzz = 0;
#pragma unroll
      for (int w = 0; w < 16; w++) {
        tsv += redf[0][w]; tsp += redf[1][w];
        tcv += redu[0][w]; tzz += redu[1][w];
      }
      // full-matrix multiset = upper-triangle doubled: top-20 mean == top-10
      // mean; counts double in numerator and denominator (cancel in means)
      out[0] = topsum * 0.1f;
      out[1] = (float)(2u * tzz);
      out[2] = tsp / (float)tcv;
      out[3] = (tsv - tsp) / (float)(TCV - tcv);
    }
  }
}

extern "C" void kernel_launch(void* const* d_in, const int* in_sizes, int n_in,
                              void* d_out, int out_size, void* d_ws,
                              size_t ws_size, hipStream_t stream) {
  const float* X = (const float*)d_in[0];
  const int* tgt = (const int*)d_in[1];
  float* out = (float*)d_out;
  char* ws = (char*)d_ws;

  float* slots = (float*)ws;
  float* top10g = slots + TOP10G_IDX;
  _Float16* Xh = (_Float16*)(ws + XH_OFF);

  prep_kernel<<<(N * D / 4) / 256, 256, 0, stream>>>((const float4*)X,
                                                     (ushort4*)Xh);
  gemm_stats_kernel<<<NBLK, 256, 0, stream>>>(Xh, tgt, slots, top10g);
  finalize_kernel<<<1, 1024, 0, stream>>>(slots, top10g, out);
}